// Round 4
// baseline (254.886 us; speedup 1.0000x reference)
//
#include <hip/hip_runtime.h>

// Problem: out0, out1, targets: [16, 21, 256, 256] f32; out2: [16, 21] f32.
// Output: scalar f32 = mean(bce(out0,t)) + 0.4*mean(bce(out1,t)) + 0.2*mean(bce(out2, presence)).
constexpr int kB = 16;
constexpr int kC = 21;
constexpr int kPerSample = kC * 256 * 256;                    // 1376256
constexpr int kN = kB * kPerSample;                           // 22020096
constexpr int kF4PerSample = kPerSample / 4;                  // 344064
constexpr int kIters = 8;                                     // float4 per thread per stream
constexpr int kD = 4;                                         // o1 delay (4 iters x 4 KB = 16 KB de-phase)
constexpr int kF4PerBlock = kIters * 256;                     // 2048
constexpr int kBlocksPerSample = kF4PerSample / kF4PerBlock;  // 168
constexpr int kGrid = kB * kBlocksPerSample;                  // 2688 blocks

// Stable BCE-with-logits term: max(x,0) - x*t + log(1+exp(-|x|)).
__device__ __forceinline__ float bce_term(float x, float t) {
    return fmaf(-t, x, fmaxf(x, 0.0f)) + __logf(1.0f + __expf(-fabsf(x)));
}

__device__ __forceinline__ float bce4(const float4& x, const float4& t) {
    return bce_term(x.x, t.x) + bce_term(x.y, t.y)
         + bce_term(x.z, t.z) + bce_term(x.w, t.w);
}

// torch.histc semantics: bin_w = 20/21, idx = clip(floor(x/bin_w), 0, 20),
// values outside [0, 20] dropped.
__device__ __forceinline__ unsigned int histbit(float x) {
    if (!(x >= 0.0f && x <= 20.0f)) return 0u;
    int idx = (int)floorf(x * (21.0f / 20.0f));
    idx = idx < 0 ? 0 : (idx > 20 ? 20 : idx);
    return 1u << idx;
}

// Kernel 1. R3 post-mortem: o0[i], o1[i], t[i] are issued at the same index
// into three 84-MiB-apart (power-of-2 congruent) arrays -> the triple hits the
// same HBM channel/bank + same cache sets every cycle; three kernel structures
// all pinned at ~2.8 TB/s (=~1/3 DRAM efficiency). Fix: o1's stream TRAILS
// o0/t by kD iterations (16 KB address de-phase). Its matching t value rides a
// kD-deep register delay line, so no element is ever read twice.
__global__ __launch_bounds__(256) void main_reduce(
    const float4* __restrict__ o0, const float4* __restrict__ o1,
    const float4* __restrict__ tg, float* __restrict__ part_sum,
    unsigned int* __restrict__ part_mask)
{
    const int tid = threadIdx.x;
    const int blk = blockIdx.x;
    const int samp = blk / kBlocksPerSample;
    const int chunk = blk - samp * kBlocksPerSample;
    const int base = samp * kF4PerSample + chunk * kF4PerBlock + tid;

    float4 th[kD];        // t delay line (registers after full unroll)
    float acc0 = 0.0f, acc1 = 0.0f;
    unsigned int m = 0u;

    #pragma unroll
    for (int k = 0; k < kIters + kD; ++k) {
        float4 a, t, b;
        if (k < kIters) {
            const int idx = base + k * 256;
            a = o0[idx];
            t = tg[idx];
        }
        if (k >= kD) {
            const int idx = base + (k - kD) * 256;
            b = o1[idx];
        }
        if (k >= kD) {
            const float4 tb = th[k % kD];   // t from iteration k-kD
            acc1 += bce4(b, tb);
        }
        if (k < kIters) {
            acc0 += bce4(a, t);
            m |= histbit(t.x) | histbit(t.y) | histbit(t.z) | histbit(t.w);
            th[k % kD] = t;                 // write AFTER the delayed read
        }
    }
    float acc = acc0 + 0.4f * acc1;

    // Wave64 shuffle reduction for both sum and mask, then cross-wave via LDS.
    #pragma unroll
    for (int off = 32; off >= 1; off >>= 1) {
        acc += __shfl_down(acc, off, 64);
        m |= (unsigned int)__shfl_down((int)m, off, 64);
    }
    __shared__ float s_red[4];
    __shared__ unsigned int s_m[4];
    if ((tid & 63) == 0) { s_red[tid >> 6] = acc; s_m[tid >> 6] = m; }
    __syncthreads();
    if (tid == 0) {
        part_sum[blk] = s_red[0] + s_red[1] + s_red[2] + s_red[3];
        part_mask[blk] = s_m[0] | s_m[1] | s_m[2] | s_m[3];
    }
}

// Kernel 2: reduce 2688 partials, build per-sample presence vectors,
// compute the 336-element SE BCE, combine all three loss terms.
__global__ __launch_bounds__(1024) void finish_kernel(
    const float* __restrict__ out2, const float* __restrict__ part_sum,
    const unsigned int* __restrict__ part_mask, float* __restrict__ out)
{
    __shared__ unsigned int s_mask[kB];
    __shared__ float s_red[16];
    __shared__ float s_red2[16];
    const int tid = threadIdx.x;
    if (tid < kB) s_mask[tid] = 0u;
    __syncthreads();

    float acc = 0.0f;
    for (int i = tid; i < kGrid; i += 1024) {
        acc += part_sum[i];
        unsigned int m = part_mask[i];
        int s = i / kBlocksPerSample;
        if (m & ~s_mask[s]) atomicOr(&s_mask[s], m);
    }
    #pragma unroll
    for (int off = 32; off >= 1; off >>= 1)
        acc += __shfl_down(acc, off, 64);
    if ((tid & 63) == 0) s_red[tid >> 6] = acc;
    __syncthreads();  // also orders the s_mask atomics

    float se = 0.0f;
    if (tid < kB * kC) {
        int b = tid / kC;
        int c = tid - b * kC;
        float tv = (float)((s_mask[b] >> c) & 1u);
        se = bce_term(out2[tid], tv);
    }
    #pragma unroll
    for (int off = 32; off >= 1; off >>= 1)
        se += __shfl_down(se, off, 64);
    if ((tid & 63) == 0) s_red2[tid >> 6] = se;
    __syncthreads();

    if (tid == 0) {
        float main_total = 0.0f, se_total = 0.0f;
        #pragma unroll
        for (int w = 0; w < 16; ++w) { main_total += s_red[w]; se_total += s_red2[w]; }
        out[0] = main_total * (1.0f / (float)kN)
               + 0.2f * (se_total / (float)(kB * kC));
    }
}

extern "C" void kernel_launch(void* const* d_in, const int* in_sizes, int n_in,
                              void* d_out, int out_size, void* d_ws, size_t ws_size,
                              hipStream_t stream) {
    const float* out0    = (const float*)d_in[0];
    const float* out1    = (const float*)d_in[1];
    const float* out2    = (const float*)d_in[2];
    const float* targets = (const float*)d_in[3];

    float*        part_sum  = (float*)d_ws;                         // kGrid floats
    unsigned int* part_mask = (unsigned int*)((char*)d_ws + 16384); // kGrid uints

    main_reduce<<<kGrid, 256, 0, stream>>>(
        (const float4*)out0, (const float4*)out1, (const float4*)targets,
        part_sum, part_mask);
    finish_kernel<<<1, 1024, 0, stream>>>(out2, part_sum, part_mask, (float*)d_out);
}

// Round 5
// 230.325 us; speedup vs baseline: 1.1066x; 1.1066x over previous
//
#include <hip/hip_runtime.h>

// Problem: out0, out1, targets: [16, 21, 256, 256] f32; out2: [16, 21] f32.
// Output: scalar f32 = mean(bce(out0,t)) + 0.4*mean(bce(out1,t)) + 0.2*mean(bce(out2, presence)).
constexpr int kB = 16;
constexpr int kC = 21;
constexpr int kPerSample = kC * 256 * 256;                    // 1376256
constexpr int kN = kB * kPerSample;                           // 22020096
constexpr int kF4PerSample = kPerSample / 4;                  // 344064
constexpr int kIters = 8;                                     // float4 per thread
constexpr int kF4PerBlock = kIters * 256;                     // 2048
constexpr int kBlocksPerSample = kF4PerSample / kF4PerBlock;  // 168
constexpr int kGrid = kB * kBlocksPerSample;                  // 2688 blocks

// Clang ext vector so __builtin_nontemporal_load works (HIP float4 is a struct).
typedef float f32x4 __attribute__((ext_vector_type(4)));

// Stable BCE-with-logits term: max(x,0) - x*t + log(1+exp(-|x|)).
__device__ __forceinline__ float bce_term(float x, float t) {
    return fmaf(-t, x, fmaxf(x, 0.0f)) + __logf(1.0f + __expf(-fabsf(x)));
}

__device__ __forceinline__ float bce4(f32x4 x, f32x4 t) {
    return bce_term(x.x, t.x) + bce_term(x.y, t.y)
         + bce_term(x.z, t.z) + bce_term(x.w, t.w);
}

// torch.histc semantics: bin_w = 20/21, idx = clip(floor(x/bin_w), 0, 20),
// values outside [0, 20] dropped.
__device__ __forceinline__ unsigned int histbit(float x) {
    if (!(x >= 0.0f && x <= 20.0f)) return 0u;
    int idx = (int)floorf(x * (21.0f / 20.0f));
    idx = idx < 0 ? 0 : (idx > 20 ? 20 : idx);
    return 1u << idx;
}

// Kernel 1. R4 post-mortem: kernel runs 100 us even when inputs are fully
// cache-resident (hbm_bytes ~ 0 replay passes) -> limiter is the CU-side
// request path, not HBM. Effective BW = 4.3 B/cy/CU = one 1-KB wave-load per
// ~L2-latency: near-zero memory parallelism, consistent with L1 set/MSHR
// serialization (all streams/blocks congruent mod 8 KB). Fix: zero-reuse
// streams -> nontemporal loads (nt flag) bypass L1 allocation entirely.
__global__ __launch_bounds__(256) void main_reduce(
    const f32x4* __restrict__ o0, const f32x4* __restrict__ o1,
    const f32x4* __restrict__ tg, float* __restrict__ part_sum,
    unsigned int* __restrict__ part_mask)
{
    const int tid = threadIdx.x;
    const int blk = blockIdx.x;
    const int samp = blk / kBlocksPerSample;
    const int chunk = blk - samp * kBlocksPerSample;
    const int base = samp * kF4PerSample + chunk * kF4PerBlock + tid;

    float acc0 = 0.0f, acc1 = 0.0f;
    unsigned int m = 0u;

    #pragma unroll
    for (int k = 0; k < kIters; ++k) {
        const int idx = base + k * 256;
        f32x4 a = __builtin_nontemporal_load(&o0[idx]);
        f32x4 b = __builtin_nontemporal_load(&o1[idx]);
        f32x4 t = __builtin_nontemporal_load(&tg[idx]);
        acc0 += bce4(a, t);
        acc1 += bce4(b, t);
        m |= histbit(t.x) | histbit(t.y) | histbit(t.z) | histbit(t.w);
    }
    float acc = acc0 + 0.4f * acc1;

    // Wave64 shuffle reduction for both sum and mask, then cross-wave via LDS.
    #pragma unroll
    for (int off = 32; off >= 1; off >>= 1) {
        acc += __shfl_down(acc, off, 64);
        m |= (unsigned int)__shfl_down((int)m, off, 64);
    }
    __shared__ float s_red[4];
    __shared__ unsigned int s_m[4];
    if ((tid & 63) == 0) { s_red[tid >> 6] = acc; s_m[tid >> 6] = m; }
    __syncthreads();
    if (tid == 0) {
        part_sum[blk] = s_red[0] + s_red[1] + s_red[2] + s_red[3];
        part_mask[blk] = s_m[0] | s_m[1] | s_m[2] | s_m[3];
    }
}

// Kernel 2: reduce 2688 partials, build per-sample presence vectors,
// compute the 336-element SE BCE, combine all three loss terms.
__global__ __launch_bounds__(1024) void finish_kernel(
    const float* __restrict__ out2, const float* __restrict__ part_sum,
    const unsigned int* __restrict__ part_mask, float* __restrict__ out)
{
    __shared__ unsigned int s_mask[kB];
    __shared__ float s_red[16];
    __shared__ float s_red2[16];
    const int tid = threadIdx.x;
    if (tid < kB) s_mask[tid] = 0u;
    __syncthreads();

    float acc = 0.0f;
    for (int i = tid; i < kGrid; i += 1024) {
        acc += part_sum[i];
        unsigned int m = part_mask[i];
        int s = i / kBlocksPerSample;
        if (m & ~s_mask[s]) atomicOr(&s_mask[s], m);
    }
    #pragma unroll
    for (int off = 32; off >= 1; off >>= 1)
        acc += __shfl_down(acc, off, 64);
    if ((tid & 63) == 0) s_red[tid >> 6] = acc;
    __syncthreads();  // also orders the s_mask atomics

    float se = 0.0f;
    if (tid < kB * kC) {
        int b = tid / kC;
        int c = tid - b * kC;
        float tv = (float)((s_mask[b] >> c) & 1u);
        se = bce_term(out2[tid], tv);
    }
    #pragma unroll
    for (int off = 32; off >= 1; off >>= 1)
        se += __shfl_down(se, off, 64);
    if ((tid & 63) == 0) s_red2[tid >> 6] = se;
    __syncthreads();

    if (tid == 0) {
        float main_total = 0.0f, se_total = 0.0f;
        #pragma unroll
        for (int w = 0; w < 16; ++w) { main_total += s_red[w]; se_total += s_red2[w]; }
        out[0] = main_total * (1.0f / (float)kN)
               + 0.2f * (se_total / (float)(kB * kC));
    }
}

extern "C" void kernel_launch(void* const* d_in, const int* in_sizes, int n_in,
                              void* d_out, int out_size, void* d_ws, size_t ws_size,
                              hipStream_t stream) {
    const float* out0    = (const float*)d_in[0];
    const float* out1    = (const float*)d_in[1];
    const float* out2    = (const float*)d_in[2];
    const float* targets = (const float*)d_in[3];

    float*        part_sum  = (float*)d_ws;                         // kGrid floats
    unsigned int* part_mask = (unsigned int*)((char*)d_ws + 16384); // kGrid uints

    main_reduce<<<kGrid, 256, 0, stream>>>(
        (const f32x4*)out0, (const f32x4*)out1, (const f32x4*)targets,
        part_sum, part_mask);
    finish_kernel<<<1, 1024, 0, stream>>>(out2, part_sum, part_mask, (float*)d_out);
}